// Round 4
// baseline (3064.890 us; speedup 1.0000x reference)
//
#include <hip/hip_runtime.h>

typedef _Float16 f16;
typedef _Float16 f16x8 __attribute__((ext_vector_type(8)));
typedef float f32x4 __attribute__((ext_vector_type(4)));

#define N_NODES 50000
#define N_EDGES 600000
#define G_GRAPHS 128
#define H 128
#define NP 50176              // 196*256, padded node count for scan
#define NTILES 1563           // ceil(50000/32)

// ---------------------------------------------------------------------------
// f0 = relu(node_f @ W_in + b_in)  -> fh (f16)
// ---------------------------------------------------------------------------
__global__ void k_f0(const float* __restrict__ node_f, const float* __restrict__ W_in,
                     const float* __restrict__ b_in, f16* __restrict__ fh)
{
    __shared__ float sW[32 * 128];
    __shared__ float sx[8][32];
    const int tid = threadIdx.x;     // 128 threads
    const int base = blockIdx.x * 8;
    for (int i = tid; i < 32 * 128; i += 128) sW[i] = W_in[i];
    for (int i = tid; i < 8 * 32; i += 128) {
        int u = i >> 5, k = i & 31;
        int n = base + u;
        sx[u][k] = (n < N_NODES) ? node_f[(size_t)n * 32 + k] : 0.0f;
    }
    __syncthreads();
    const float bj = b_in[tid];
    #pragma unroll
    for (int u = 0; u < 8; ++u) {
        int n = base + u;
        if (n >= N_NODES) break;
        float acc = bj;
        #pragma unroll
        for (int k = 0; k < 32; ++k) acc = fmaf(sx[u][k], sW[k * 128 + tid], acc);
        fh[(size_t)n * H + tid] = (f16)fmaxf(acc, 0.0f);
    }
}

// ---------------------------------------------------------------------------
// CSR build: histogram, scan (3 kernels), scatter
// ---------------------------------------------------------------------------
__global__ void k_hist(const int* __restrict__ dst, int* __restrict__ cnt)
{
    int e = blockIdx.x * 256 + threadIdx.x;
    if (e < N_EDGES) atomicAdd(&cnt[dst[e]], 1);
}

__global__ void k_scanA(const int* __restrict__ cnt, int* __restrict__ rowptr,
                        int* __restrict__ bsum)
{
    __shared__ int s[256];
    const int t = threadIdx.x;
    const int i = blockIdx.x * 256 + t;
    int v = cnt[i];
    s[t] = v;
    __syncthreads();
    #pragma unroll
    for (int off = 1; off < 256; off <<= 1) {
        int x = (t >= off) ? s[t - off] : 0;
        __syncthreads();
        s[t] += x;
        __syncthreads();
    }
    rowptr[i] = s[t] - v;            // exclusive, pre-offset
    if (t == 255) bsum[blockIdx.x] = s[255];
}

__global__ void k_scanB(const int* __restrict__ bsum, int* __restrict__ boff)
{
    __shared__ int s[256];
    const int t = threadIdx.x;
    int v = (t < 196) ? bsum[t] : 0;
    s[t] = v;
    __syncthreads();
    #pragma unroll
    for (int off = 1; off < 256; off <<= 1) {
        int x = (t >= off) ? s[t - off] : 0;
        __syncthreads();
        s[t] += x;
        __syncthreads();
    }
    boff[t] = s[t] - v;
}

__global__ void k_scanC(int* __restrict__ rowptr, const int* __restrict__ boff)
{
    int i = blockIdx.x * 256 + threadIdx.x;
    rowptr[i] += boff[blockIdx.x];
}

// scatter edges into dst-sorted order; also compute sq and f16 edge feats
__global__ void k_scatter(const float* __restrict__ edge_w, const int* __restrict__ src,
                          const int* __restrict__ dst, const float* __restrict__ node_x,
                          const int* __restrict__ rowptr, int* __restrict__ fill,
                          int* __restrict__ perm_src, float* __restrict__ perm_sq,
                          f16* __restrict__ perm_ewh)
{
    int e = blockIdx.x * 256 + threadIdx.x;
    if (e >= N_EDGES) return;
    int s = src[e], d = dst[e];
    float dx = node_x[s * 3 + 0] - node_x[d * 3 + 0];
    float dy = node_x[s * 3 + 1] - node_x[d * 3 + 1];
    float dz = node_x[s * 3 + 2] - node_x[d * 3 + 2];
    float sq = dx * dx + dy * dy + dz * dz;
    const float4* pw = (const float4*)(edge_w + (size_t)e * 16);
    float4 w0 = pw[0], w1 = pw[1], w2 = pw[2], w3 = pw[3];
    int p = rowptr[d] + atomicAdd(&fill[d], 1);
    perm_src[p] = s;
    perm_sq[p] = sq;
    f16x8 v0, v1;
    v0[0] = (f16)w0.x; v0[1] = (f16)w0.y; v0[2] = (f16)w0.z; v0[3] = (f16)w0.w;
    v0[4] = (f16)w1.x; v0[5] = (f16)w1.y; v0[6] = (f16)w1.z; v0[7] = (f16)w1.w;
    v1[0] = (f16)w2.x; v1[1] = (f16)w2.y; v1[2] = (f16)w2.z; v1[3] = (f16)w2.w;
    v1[4] = (f16)w3.x; v1[5] = (f16)w3.y; v1[6] = (f16)w3.z; v1[7] = (f16)w3.w;
    f16x8* q = (f16x8*)(perm_ewh + (size_t)p * 16);
    q[0] = v0; q[1] = v1;
}

// ---------------------------------------------------------------------------
// Fused per-layer kernel: block owns 32 dst nodes + all their edges.
//   per edge-chunk(32): w=relu(ew@We+be); h1=relu([fs|fd|w|sq]@W1+b1);
//   m=relu(h1@W2+b2); LDS-accumulate by dst. Then u=acc+f_old and the
//   update MLP, storing fh_out. No global atomics.
// ---------------------------------------------------------------------------
__global__ __launch_bounds__(512, 4) void k_layer(
    const f16* __restrict__ fh_in, f16* __restrict__ fh_out,
    const int* __restrict__ rowptr, const int* __restrict__ perm_src,
    const float* __restrict__ perm_sq, const f16* __restrict__ perm_ewh,
    const float* __restrict__ W_e, const float* __restrict__ b_e,
    const float* __restrict__ W1, const float* __restrict__ b1,
    const float* __restrict__ W2, const float* __restrict__ b2,
    const float* __restrict__ U1, const float* __restrict__ ub1,
    const float* __restrict__ U2, const float* __restrict__ ub2)
{
    const int tid = threadIdx.x;     // 512
    const int wave = tid >> 6;       // 0..7, owns 16 output cols
    const int lane = tid & 63;
    const int l16 = lane & 15;
    const int lq  = lane >> 4;
    const int col = wave * 16 + l16; // 0..127

    // ---- message weight fragments (68 VGPRs) ----
    f16x8 wef, w1f[12], w2f[4];
    #pragma unroll
    for (int j = 0; j < 8; ++j) {
        int k = lq * 8 + j;
        wef[j] = (k < 16) ? (f16)W_e[(size_t)k * H + col] : (f16)0.0f;
    }
    #pragma unroll
    for (int k = 0; k < 12; ++k)
        #pragma unroll
        for (int j = 0; j < 8; ++j)
            w1f[k][j] = (f16)W1[(size_t)(k * 32 + lq * 8 + j) * H + col];
    #pragma unroll
    for (int k = 0; k < 4; ++k)
        #pragma unroll
        for (int j = 0; j < 8; ++j)
            w2f[k][j] = (f16)W2[(size_t)(k * 32 + lq * 8 + j) * H + col];
    float w1last = W1[(size_t)384 * H + col];
    float b1v = b1[col], b2v = b2[col], bev = b_e[col];

    __shared__ alignas(16) f16 Atile[32][392];      // 25.1 KB
    __shared__ float s_acc[33][132];                 // 17.4 KB (row 32 = trash)
    __shared__ alignas(16) f16 s_fd[32][128];        // 8.2 KB (fh of owned nodes)
    __shared__ alignas(16) f16 s_ew[32][16];         // 1 KB
    __shared__ int s_rowptr[33];
    __shared__ int s_srcv[32];
    __shared__ int s_dloc[32];
    __shared__ float s_sq[32];

    const int n0 = blockIdx.x * 32;
    if (tid < 33) s_rowptr[tid] = rowptr[n0 + tid];
    for (int i = tid; i < 33 * 132; i += 512) ((float*)s_acc)[i] = 0.0f;
    {
        // 32 rows x 16 lanes; each lane loads one int4 (8 f16) -> full 128 cols
        int row = tid >> 4, ch = tid & 15;
        int n = n0 + row; if (n >= N_NODES) n = 0;
        ((int4*)&s_fd[row][0])[ch] = ((const int4*)(fh_in + (size_t)n * H))[ch];
    }
    __syncthreads();
    const int rs = s_rowptr[0], re = s_rowptr[32];

    for (int e0 = rs; e0 < re; e0 += 32) {
        // --- per-chunk edge metadata (32 threads) ---
        if (tid < 32) {
            int e = e0 + tid;
            int sv = 0; float sqv = 0.0f; int dl = 32;
            f16x8 v0, v1;
            #pragma unroll
            for (int j = 0; j < 8; ++j) { v0[j] = (f16)0.0f; v1[j] = (f16)0.0f; }
            if (e < re) {
                sv = perm_src[e];
                sqv = perm_sq[e];
                int lo = 0, hi = 32;
                #pragma unroll
                for (int it = 0; it < 5; ++it) {
                    int mid = (lo + hi) >> 1;
                    if (e >= s_rowptr[mid]) lo = mid; else hi = mid;
                }
                dl = lo;
                const f16x8* q = (const f16x8*)(perm_ewh + (size_t)e * 16);
                v0 = q[0]; v1 = q[1];
            }
            s_srcv[tid] = sv; s_sq[tid] = sqv; s_dloc[tid] = dl;
            ((f16x8*)&s_ew[tid][0])[0] = v0;
            ((f16x8*)&s_ew[tid][0])[1] = v1;
        }
        __syncthreads();

        // --- stage A rows: [f_src | f_dst], each lane: 1 int4 of src + 1 of dst ---
        {
            int row = tid >> 4, ch = tid & 15;
            int sv = s_srcv[row];
            int dl = s_dloc[row]; if (dl > 31) dl = 0;
            ((int4*)&Atile[row][0])[ch]   = ((const int4*)(fh_in + (size_t)sv * H))[ch];
            ((int4*)&Atile[row][128])[ch] = ((const int4*)&s_fd[dl][0])[ch];
        }
        // --- w = relu(ew @ We + be) -> cols 256..383 ---
        #pragma unroll
        for (int m = 0; m < 2; ++m) {
            f16x8 a;
            if (lq < 2) {
                a = *(const f16x8*)&s_ew[m * 16 + l16][lq * 8];
            } else {
                #pragma unroll
                for (int j = 0; j < 8; ++j) a[j] = (f16)0.0f;
            }
            f32x4 c = {bev, bev, bev, bev};
            c = __builtin_amdgcn_mfma_f32_16x16x32_f16(a, wef, c, 0, 0, 0);
            #pragma unroll
            for (int r = 0; r < 4; ++r)
                Atile[m * 16 + lq * 4 + r][256 + col] = (f16)fmaxf(c[r], 0.0f);
        }
        __syncthreads();

        // --- mm1: h1 = relu(A @ W1 + sq*w1last + b1) ---
        f32x4 acc1[2];
        #pragma unroll
        for (int m = 0; m < 2; ++m)
            #pragma unroll
            for (int r = 0; r < 4; ++r)
                acc1[m][r] = fmaf(s_sq[m * 16 + lq * 4 + r], w1last, b1v);
        #pragma unroll
        for (int k = 0; k < 12; ++k) {
            #pragma unroll
            for (int m = 0; m < 2; ++m) {
                f16x8 a = *(const f16x8*)&Atile[m * 16 + l16][k * 32 + lq * 8];
                acc1[m] = __builtin_amdgcn_mfma_f32_16x16x32_f16(a, w1f[k], acc1[m], 0, 0, 0);
            }
        }
        __syncthreads();
        #pragma unroll
        for (int m = 0; m < 2; ++m)
            #pragma unroll
            for (int r = 0; r < 4; ++r)
                Atile[m * 16 + lq * 4 + r][col] = (f16)fmaxf(acc1[m][r], 0.0f);
        __syncthreads();

        // --- mm2 + LDS accumulate by dst ---
        f32x4 acc2[2];
        #pragma unroll
        for (int m = 0; m < 2; ++m) {
            f32x4 c = {b2v, b2v, b2v, b2v};
            acc2[m] = c;
        }
        #pragma unroll
        for (int k = 0; k < 4; ++k) {
            #pragma unroll
            for (int m = 0; m < 2; ++m) {
                f16x8 a = *(const f16x8*)&Atile[m * 16 + l16][k * 32 + lq * 8];
                acc2[m] = __builtin_amdgcn_mfma_f32_16x16x32_f16(a, w2f[k], acc2[m], 0, 0, 0);
            }
        }
        #pragma unroll
        for (int m = 0; m < 2; ++m)
            #pragma unroll
            for (int r = 0; r < 4; ++r) {
                int ri = m * 16 + lq * 4 + r;
                atomicAdd(&s_acc[s_dloc[ri]][col], fmaxf(acc2[m][r], 0.0f));
            }
        __syncthreads();
    }

    // ---- update MLP: f_new = relu(relu((acc+f_old)@U1+b1u)@U2+b2u) ----
    // overwrite msg-frag registers with update weights (keeps VGPR peak low)
    #pragma unroll
    for (int k = 0; k < 4; ++k)
        #pragma unroll
        for (int j = 0; j < 8; ++j) {
            w1f[k][j] = (f16)U1[(size_t)(k * 32 + lq * 8 + j) * H + col];
            w2f[k][j] = (f16)U2[(size_t)(k * 32 + lq * 8 + j) * H + col];
        }
    b1v = ub1[col]; b2v = ub2[col];

    {
        // u = acc + f_old: 32 rows x 16 lanes, each lane 8 cols -> full 128
        int row = tid >> 4, ch = tid & 15;
        f16x8 t;
        #pragma unroll
        for (int j = 0; j < 8; ++j)
            t[j] = (f16)(s_acc[row][ch * 8 + j] + (float)s_fd[row][ch * 8 + j]);
        *((f16x8*)&Atile[row][0] + ch) = t;
    }
    __syncthreads();

    f32x4 a1[2];
    #pragma unroll
    for (int m = 0; m < 2; ++m) {
        f32x4 c = {b1v, b1v, b1v, b1v};
        a1[m] = c;
    }
    #pragma unroll
    for (int k = 0; k < 4; ++k) {
        #pragma unroll
        for (int m = 0; m < 2; ++m) {
            f16x8 a = *(const f16x8*)&Atile[m * 16 + l16][k * 32 + lq * 8];
            a1[m] = __builtin_amdgcn_mfma_f32_16x16x32_f16(a, w1f[k], a1[m], 0, 0, 0);
        }
    }
    __syncthreads();
    #pragma unroll
    for (int m = 0; m < 2; ++m)
        #pragma unroll
        for (int r = 0; r < 4; ++r)
            Atile[m * 16 + lq * 4 + r][col] = (f16)fmaxf(a1[m][r], 0.0f);
    __syncthreads();

    f32x4 a2[2];
    #pragma unroll
    for (int m = 0; m < 2; ++m) {
        f32x4 c = {b2v, b2v, b2v, b2v};
        a2[m] = c;
    }
    #pragma unroll
    for (int k = 0; k < 4; ++k) {
        #pragma unroll
        for (int m = 0; m < 2; ++m) {
            f16x8 a = *(const f16x8*)&Atile[m * 16 + l16][k * 32 + lq * 8];
            a2[m] = __builtin_amdgcn_mfma_f32_16x16x32_f16(a, w2f[k], a2[m], 0, 0, 0);
        }
    }
    #pragma unroll
    for (int m = 0; m < 2; ++m)
        #pragma unroll
        for (int r = 0; r < 4; ++r) {
            int row = m * 16 + lq * 4 + r;
            int n = n0 + row;
            if (n < N_NODES)
                fh_out[(size_t)n * H + col] = (f16)fmaxf(a2[m][r], 0.0f);
        }
}

// ---------------------------------------------------------------------------
// Per-graph mean/max readout (graph_ids sorted; f >= 0)
// ---------------------------------------------------------------------------
__global__ void k_readout(const f16* __restrict__ fh, const int* __restrict__ gid,
                          float* __restrict__ gsum, float* __restrict__ gmax,
                          int* __restrict__ gcnt)
{
    __shared__ int s_gid[64];
    const int tid = threadIdx.x;            // 128 threads
    const int base = blockIdx.x * 64;
    if (tid < 64) s_gid[tid] = (base + tid < N_NODES) ? gid[base + tid] : -1;
    __syncthreads();
    if (tid < 64 && base + tid < N_NODES) atomicAdd(&gcnt[s_gid[tid]], 1);

    float lsum = 0.0f, lmax = 0.0f;
    int cur = s_gid[0];
    if (cur >= 0) {
        for (int i = 0; i < 64; ++i) {
            int g = s_gid[i];
            if (g < 0) break;
            if (g != cur) {
                unsafeAtomicAdd(&gsum[(size_t)cur * H + tid], lsum);
                atomicMax((int*)&gmax[(size_t)cur * H + tid], __float_as_int(lmax));
                lsum = 0.0f; lmax = 0.0f; cur = g;
            }
            float v = (float)fh[(size_t)(base + i) * H + tid];
            lsum += v;
            lmax = fmaxf(lmax, v);
        }
        unsafeAtomicAdd(&gsum[(size_t)cur * H + tid], lsum);
        atomicMax((int*)&gmax[(size_t)cur * H + tid], __float_as_int(lmax));
    }
}

__global__ void k_out(const float* __restrict__ gsum, const float* __restrict__ gmax,
                      const int* __restrict__ gcnt, const float* __restrict__ W_out,
                      const float* __restrict__ b_out, float* __restrict__ out)
{
    __shared__ float sm[128], sx[128];
    const int g = blockIdx.x, t = threadIdx.x;
    const float inv = 1.0f / fmaxf((float)gcnt[g], 1.0f);
    sm[t] = gsum[(size_t)g * H + t] * inv;
    sx[t] = gmax[(size_t)g * H + t];
    __syncthreads();
    float acc = b_out[t];
    for (int k = 0; k < H; ++k) {
        acc = fmaf(sm[k], W_out[(size_t)k * 128 + t], acc);
        acc = fmaf(sx[k], W_out[(size_t)(128 + k) * 128 + t], acc);
    }
    out[(size_t)g * 128 + t] = acc;
}

// ---------------------------------------------------------------------------
extern "C" void kernel_launch(void* const* d_in, const int* in_sizes, int n_in,
                              void* d_out, int out_size, void* d_ws, size_t ws_size,
                              hipStream_t stream)
{
    const float* node_f = (const float*)d_in[0];
    const float* node_x = (const float*)d_in[1];
    const float* edge_w = (const float*)d_in[2];
    const int*   src    = (const int*)d_in[3];
    const int*   dst    = (const int*)d_in[4];
    const int*   gid    = (const int*)d_in[5];
    const float* W_in   = (const float*)d_in[6];
    const float* b_in   = (const float*)d_in[7];
    const float* W_e    = (const float*)d_in[8];
    const float* b_e    = (const float*)d_in[9];
    const float* msg_W1 = (const float*)d_in[10];
    const float* msg_b1 = (const float*)d_in[11];
    const float* msg_W2 = (const float*)d_in[12];
    const float* msg_b2 = (const float*)d_in[13];
    const float* upd_W1 = (const float*)d_in[14];
    const float* upd_b1 = (const float*)d_in[15];
    const float* upd_W2 = (const float*)d_in[16];
    const float* upd_b2 = (const float*)d_in[17];
    const float* W_out  = (const float*)d_in[18];
    const float* b_out  = (const float*)d_in[19];
    float* out = (float*)d_out;

    char* ws = (char*)d_ws;
    size_t off = 0;
    f16*   fhA      = (f16*)(ws + off);   off += (size_t)N_NODES * H * 2;      // 12.8 MB
    f16*   fhB      = (f16*)(ws + off);   off += (size_t)N_NODES * H * 2;      // 12.8 MB
    f16*   perm_ewh = (f16*)(ws + off);   off += (size_t)N_EDGES * 16 * 2;     // 19.2 MB
    int*   perm_src = (int*)(ws + off);   off += (size_t)N_EDGES * 4;          // 2.4 MB
    float* perm_sq  = (float*)(ws + off); off += (size_t)N_EDGES * 4;          // 2.4 MB
    int*   rowptr   = (int*)(ws + off);   off += (size_t)NP * 4;
    int*   cnt      = (int*)(ws + off);   off += (size_t)NP * 4;               // also 'fill'
    int*   bsum     = (int*)(ws + off);   off += 256 * 4;
    int*   boff     = (int*)(ws + off);   off += 256 * 4;
    float* gsum     = (float*)(ws + off); off += (size_t)G_GRAPHS * H * 4;
    float* gmax     = (float*)(ws + off); off += (size_t)G_GRAPHS * H * 4;
    int*   gcnt     = (int*)(ws + off);   off += (size_t)G_GRAPHS * 4;

    k_f0<<<(N_NODES + 7) / 8, 128, 0, stream>>>(node_f, W_in, b_in, fhA);

    (void)hipMemsetAsync(cnt, 0, (size_t)NP * 4, stream);
    k_hist<<<(N_EDGES + 255) / 256, 256, 0, stream>>>(dst, cnt);
    k_scanA<<<NP / 256, 256, 0, stream>>>(cnt, rowptr, bsum);
    k_scanB<<<1, 256, 0, stream>>>(bsum, boff);
    k_scanC<<<NP / 256, 256, 0, stream>>>(rowptr, boff);
    (void)hipMemsetAsync(cnt, 0, (size_t)NP * 4, stream);
    k_scatter<<<(N_EDGES + 255) / 256, 256, 0, stream>>>(edge_w, src, dst, node_x,
                                                         rowptr, cnt, perm_src,
                                                         perm_sq, perm_ewh);

    for (int l = 0; l < 4; ++l) {
        const f16* fin  = (l & 1) ? fhB : fhA;
        f16*       fout = (l & 1) ? fhA : fhB;
        k_layer<<<NTILES, 512, 0, stream>>>(fin, fout, rowptr, perm_src, perm_sq, perm_ewh,
                                            W_e, b_e,
                                            msg_W1 + (size_t)l * 385 * H, msg_b1 + (size_t)l * H,
                                            msg_W2 + (size_t)l * H * H,  msg_b2 + (size_t)l * H,
                                            upd_W1 + (size_t)l * H * H,  upd_b1 + (size_t)l * H,
                                            upd_W2 + (size_t)l * H * H,  upd_b2 + (size_t)l * H);
    }

    (void)hipMemsetAsync(gsum, 0, (size_t)G_GRAPHS * H * 4, stream);
    (void)hipMemsetAsync(gmax, 0, (size_t)G_GRAPHS * H * 4, stream);
    (void)hipMemsetAsync(gcnt, 0, (size_t)G_GRAPHS * 4, stream);
    k_readout<<<(N_NODES + 63) / 64, 128, 0, stream>>>(fhA, gid, gsum, gmax, gcnt);
    k_out<<<G_GRAPHS, 128, 0, stream>>>(gsum, gmax, gcnt, W_out, b_out, out);
}